// Round 4
// baseline (1539.338 us; speedup 1.0000x reference)
//
#include <hip/hip_runtime.h>
#include <hip/hip_bf16.h>

#define N_FEAT 128
#define HID 16
#define NCLS 10
#define NGRAPH 1024

__device__ __forceinline__ float u2f(unsigned int u) {
    union { unsigned int u; float f; } c; c.u = u; return c.f;
}
__device__ __forceinline__ float bf2f(__hip_bfloat16 b) {
    return __bfloat162float(b);
}
// load float element i from buffer that is bf16 (isbf=1) or fp32 (isbf=0)
__device__ __forceinline__ float ldw(const void* __restrict__ p, int i, int isbf) {
    return isbf ? bf2f(((const __hip_bfloat16*)p)[i]) : ((const float*)p)[i];
}

// ---------------------------------------------------------------------------
// K0: runtime dtype probes (these made R3 pass — keep).
// flags[0]: 1 if indices are int64 (odd words of positive int64s are all 0).
// flags[1]: 1 if float tensors are bf16 (low-half exponent-field statistics).
__global__ void k_detect(const int* __restrict__ ei,
                         const unsigned int* __restrict__ xw,
                         int* __restrict__ flags) {
    if (blockIdx.x == 0 && threadIdx.x == 0) {
        int nz = 0;
        for (int i = 1; i < 256; i += 2) nz |= ei[i];
        flags[0] = (nz == 0) ? 1 : 0;
        int cnt = 0;
        for (int i = 0; i < 64; i++) {
            unsigned int ef = xw[i] & 0x7F80u;
            if (ef >= 0x3C00u && ef <= 0x4080u) cnt++;
        }
        flags[1] = (cnt >= 32) ? 1 : 0;
    }
}

__global__ void k_zero_int(int* __restrict__ p, int n) {
    int i = blockIdx.x * blockDim.x + threadIdx.x;
    if (i < n) p[i] = 0;
}

// ---------------------------------------------------------------------------
// K1: h0[i] = emb[argmax(x[i,:])] — one 64-lane wave per node.
__global__ void k_argmax_embed(const void* __restrict__ x,
                               const void* __restrict__ emb,
                               const int* __restrict__ flags,
                               float* __restrict__ h, int n) {
    int wave = (int)((blockIdx.x * (unsigned)blockDim.x + threadIdx.x) >> 6);
    int lane = threadIdx.x & 63;
    if (wave >= n) return;
    int isbf = flags[1];
    float v0, v1;
    if (isbf) {
        const unsigned int* row =
            (const unsigned int*)((const __hip_bfloat16*)x + (size_t)wave * N_FEAT);
        unsigned int u = row[lane];
        v0 = u2f(u << 16);
        v1 = u2f(u & 0xffff0000u);
    } else {
        const float2* row = (const float2*)((const float*)x + (size_t)wave * N_FEAT);
        float2 u = row[lane];
        v0 = u.x; v1 = u.y;
    }
    float bv; int bi;
    if (v1 > v0) { bv = v1; bi = 2 * lane + 1; }
    else         { bv = v0; bi = 2 * lane; }
    #pragma unroll
    for (int off = 1; off < 64; off <<= 1) {
        float ov = __shfl_xor(bv, off);
        int   oi = __shfl_xor(bi, off);
        if (ov > bv || (ov == bv && oi < bi)) { bv = ov; bi = oi; }
    }
    if (lane < HID)
        h[(size_t)wave * HID + lane] = ldw(emb, bi * HID + lane, isbf);
}

// ---------------------------------------------------------------------------
// CSR build (once per call, reused by all 3 layers)
// K2a: count in-degrees into dega[0..n)
__global__ void k_count(const int* __restrict__ ei, const int* __restrict__ flags,
                        int* __restrict__ dega, int e) {
    int i = blockIdx.x * blockDim.x + threadIdx.x;
    if (i >= e) return;
    int sh = flags[0];
    int d = ei[((size_t)(e + i)) << sh];
    atomicAdd(&dega[d], 1);
}

// K2b: in-place exclusive scan of dega[0..n) — single block of 1024 threads.
__global__ void k_scan(int* __restrict__ dega, int n) {
    __shared__ int ls[1024];
    int t = threadIdx.x;
    int chunk = (n + 1023) >> 10;
    int s0 = t * chunk;
    int s1 = min(n, s0 + chunk);
    int sum = 0;
    for (int i = s0; i < s1; i++) sum += dega[i];
    ls[t] = sum;
    __syncthreads();
    #pragma unroll
    for (int off = 1; off < 1024; off <<= 1) {
        int v = (t >= off) ? ls[t - off] : 0;
        __syncthreads();
        ls[t] += v;
        __syncthreads();
    }
    int run = ls[t] - sum;           // exclusive prefix
    for (int i = s0; i < s1; i++) {
        int old = dega[i];
        dega[i] = run;
        run += old;
    }
}

// K2c: fill col buckets. pos atomics destroy dega -> afterwards
// dega[d] == end of bucket d (== original offset of d+1); lo(d)=dega[d-1].
__global__ void k_fill(const int* __restrict__ ei, const int* __restrict__ flags,
                       int* __restrict__ dega, int* __restrict__ col, int e) {
    int i = blockIdx.x * blockDim.x + threadIdx.x;
    if (i >= e) return;
    int sh = flags[0];
    int s = ei[((size_t)i) << sh];
    int d = ei[((size_t)(e + i)) << sh];
    int pos = atomicAdd(&dega[d], 1);
    col[pos] = s;
}

// ---------------------------------------------------------------------------
// K3: fused gather + combine, layers 1/2.
// One wave per node: 4 subgroups x 16 lanes; subgroup j walks edges lo+j,
// lo+j+4, ... ; lane f reads h[src][f] (coalesced 64B row per edge).
// Then mean, Wl/Wr matmul via readlane-broadcast, L2-norm, ReLU.
__global__ void k_gc(const int* __restrict__ col, const int* __restrict__ off,
                     const float* __restrict__ hin,
                     const void* __restrict__ Wl, const void* __restrict__ bia,
                     const void* __restrict__ Wr, const int* __restrict__ flags,
                     float* __restrict__ hout, int n) {
    __shared__ float wl[HID][HID], wr[HID][HID], bb[HID];
    int t = threadIdx.x;
    int isbf = flags[1];
    if (t < HID * HID) {
        wl[t >> 4][t & 15] = ldw(Wl, t, isbf);
        wr[t >> 4][t & 15] = ldw(Wr, t, isbf);
    }
    if (t < HID) bb[t] = ldw(bia, t, isbf);
    __syncthreads();
    int node = blockIdx.x * 4 + (t >> 6);
    if (node >= n) return;
    int lane = t & 63;
    int f = lane & 15;
    int sub = lane >> 4;
    int lo = (node == 0) ? 0 : off[node - 1];
    int hi = off[node];
    float acc = 0.0f;
    int eidx = lo + sub;
    for (; eidx + 4 < hi; eidx += 8) {           // 2-edge unroll for MLP
        int s0 = col[eidx];
        int s1 = col[eidx + 4];
        acc += hin[(size_t)s0 * HID + f];
        acc += hin[(size_t)s1 * HID + f];
    }
    if (eidx < hi) {
        int s0 = col[eidx];
        acc += hin[(size_t)s0 * HID + f];
    }
    acc += __shfl_xor(acc, 16);
    acc += __shfl_xor(acc, 32);                  // every lane: bucket sum for its f
    int deg = hi - lo;
    float a = acc / fmaxf((float)deg, 1.0f);
    float hb = hin[(size_t)node * HID + f];
    float o = bb[f];
    #pragma unroll
    for (int k = 0; k < HID; k++)
        o += __shfl(a, k) * wl[f][k] + __shfl(hb, k) * wr[f][k];
    float sq = o * o;
    #pragma unroll
    for (int off2 = 1; off2 < 16; off2 <<= 1) sq += __shfl_xor(sq, off2);
    float innorm = 1.0f / fmaxf(sqrtf(sq), 1e-12f);
    o = fmaxf(o * innorm, 0.0f);
    if (lane < HID) hout[(size_t)node * HID + lane] = o;
}

// K4: fused gather + combine, layer 3 (out dim 10, no ReLU) -> h3 [n,10]
__global__ void k_gc3(const int* __restrict__ col, const int* __restrict__ off,
                      const float* __restrict__ hin,
                      const void* __restrict__ Wl, const void* __restrict__ bia,
                      const void* __restrict__ Wr, const int* __restrict__ flags,
                      float* __restrict__ h3, int n) {
    __shared__ float wl[HID][HID], wr[HID][HID], bb[HID];
    int t = threadIdx.x;
    int isbf = flags[1];
    if (t < HID * HID) {                          // rows 10..15 zero-padded
        int r = t >> 4, c = t & 15;
        wl[r][c] = (r < NCLS) ? ldw(Wl, t - (r - min(r, NCLS)) * 0 + 0, isbf) : 0.0f;
        // note: Wl is [10][16] row-major; element (r,c) = r*16+c for r<10
        if (r < NCLS) { wl[r][c] = ldw(Wl, r * HID + c, isbf); wr[r][c] = ldw(Wr, r * HID + c, isbf); }
        else          { wl[r][c] = 0.0f; wr[r][c] = 0.0f; }
    }
    if (t < HID) bb[t] = (t < NCLS) ? ldw(bia, t, isbf) : 0.0f;
    __syncthreads();
    int node = blockIdx.x * 4 + (t >> 6);
    if (node >= n) return;
    int lane = t & 63;
    int f = lane & 15;
    int sub = lane >> 4;
    int lo = (node == 0) ? 0 : off[node - 1];
    int hi = off[node];
    float acc = 0.0f;
    int eidx = lo + sub;
    for (; eidx + 4 < hi; eidx += 8) {
        int s0 = col[eidx];
        int s1 = col[eidx + 4];
        acc += hin[(size_t)s0 * HID + f];
        acc += hin[(size_t)s1 * HID + f];
    }
    if (eidx < hi) {
        int s0 = col[eidx];
        acc += hin[(size_t)s0 * HID + f];
    }
    acc += __shfl_xor(acc, 16);
    acc += __shfl_xor(acc, 32);
    int deg = hi - lo;
    float a = acc / fmaxf((float)deg, 1.0f);
    float hb = hin[(size_t)node * HID + f];
    float o = bb[f];
    #pragma unroll
    for (int k = 0; k < HID; k++)
        o += __shfl(a, k) * wl[f][k] + __shfl(hb, k) * wr[f][k];
    float sq = o * o;                             // rows >=10 give o=0
    #pragma unroll
    for (int off2 = 1; off2 < 16; off2 <<= 1) sq += __shfl_xor(sq, off2);
    float innorm = 1.0f / fmaxf(sqrtf(sq), 1e-12f);
    o = o * innorm;
    if (lane < NCLS) h3[(size_t)node * NCLS + lane] = o;
}

// ---------------------------------------------------------------------------
// K5: per-graph mean pool (batch sorted -> binary search) + softmax.
__device__ __forceinline__ int lbound(const int* __restrict__ a, int n, int key, int sh) {
    int lo = 0, hi = n;
    while (lo < hi) {
        int mid = (lo + hi) >> 1;
        if (a[((size_t)mid) << sh] < key) lo = mid + 1; else hi = mid;
    }
    return lo;
}

__global__ void k_pool_softmax(const float* __restrict__ h3,
                               const int* __restrict__ batch,
                               const int* __restrict__ flags,
                               void* __restrict__ out, int n) {
    int g = blockIdx.x;
    int lane = threadIdx.x;
    int sh = flags[0];
    int lo = lbound(batch, n, g, sh);
    int hi = lbound(batch, n, g + 1, sh);
    float acc[NCLS];
    #pragma unroll
    for (int c = 0; c < NCLS; c++) acc[c] = 0.0f;
    for (int i = lo + lane; i < hi; i += 64) {
        const float* r = h3 + (size_t)i * NCLS;
        #pragma unroll
        for (int c = 0; c < NCLS; c++) acc[c] += r[c];
    }
    #pragma unroll
    for (int c = 0; c < NCLS; c++) {
        #pragma unroll
        for (int off = 1; off < 64; off <<= 1)
            acc[c] += __shfl_xor(acc[c], off);
    }
    float invc = 1.0f / fmaxf((float)(hi - lo), 1.0f);
    float m = -1e30f;
    #pragma unroll
    for (int c = 0; c < NCLS; c++) { acc[c] *= invc; m = fmaxf(m, acc[c]); }
    float s = 0.0f;
    #pragma unroll
    for (int c = 0; c < NCLS; c++) { acc[c] = expf(acc[c] - m); s += acc[c]; }
    float invs = 1.0f / s;
    if (lane < NCLS) {
        float v = acc[lane] * invs;
        size_t idx = (size_t)g * NCLS + lane;
        if (flags[1]) ((__hip_bfloat16*)out)[idx] = __float2bfloat16(v);
        else          ((float*)out)[idx] = v;
    }
}

// ---------------------------------------------------------------------------
extern "C" void kernel_launch(void* const* d_in, const int* in_sizes, int n_in,
                              void* d_out, int out_size, void* d_ws, size_t ws_size,
                              hipStream_t stream) {
    const void* x   = d_in[0];
    const int*  ei  = (const int*)d_in[1];
    const int*  bat = (const int*)d_in[2];
    const void* emb = d_in[3];
    const void* W1l = d_in[4];  const void* b1 = d_in[5];  const void* W1r = d_in[6];
    const void* W2l = d_in[7];  const void* b2 = d_in[8];  const void* W2r = d_in[9];
    const void* W3l = d_in[10]; const void* b3 = d_in[11]; const void* W3r = d_in[12];

    int n = in_sizes[0] / N_FEAT;
    int e = in_sizes[1] / 2;

    // ws layout: hcur[n*16] f | hnext[n*16] f (reused for h3[n,10]) |
    //            dega[n+1] int | col[e] int | flags[2] int   (~38.9 MB)
    float* hcur  = (float*)d_ws;
    float* hnext = hcur + (size_t)n * HID;
    int*   dega  = (int*)(hnext + (size_t)n * HID);
    int*   col   = dega + (n + 1);
    int*   flags = col + e;
    float* h3    = hnext;

    int egrid = (e + 255) / 256;
    int ngrid4 = (n + 3) / 4;

    // probes + initial embedding + CSR build
    k_detect<<<1, 64, 0, stream>>>(ei, (const unsigned int*)x, flags);
    k_argmax_embed<<<ngrid4, 256, 0, stream>>>(x, emb, flags, hcur, n);
    k_zero_int<<<(n + 256) / 256, 256, 0, stream>>>(dega, n + 1);
    k_count<<<egrid, 256, 0, stream>>>(ei, flags, dega, e);
    k_scan<<<1, 1024, 0, stream>>>(dega, n);
    k_fill<<<egrid, 256, 0, stream>>>(ei, flags, dega, col, e);

    // 3 fused gather+combine layers (no atomics, no agg buffer)
    k_gc <<<ngrid4, 256, 0, stream>>>(col, dega, hcur,  W1l, b1, W1r, flags, hnext, n);
    k_gc <<<ngrid4, 256, 0, stream>>>(col, dega, hnext, W2l, b2, W2r, flags, hcur,  n);
    k_gc3<<<ngrid4, 256, 0, stream>>>(col, dega, hcur,  W3l, b3, W3r, flags, h3,    n);

    // pool + softmax
    k_pool_softmax<<<NGRAPH, 64, 0, stream>>>(h3, bat, flags, d_out, n);
}

// Round 5
// 1079.539 us; speedup vs baseline: 1.4259x; 1.4259x over previous
//
#include <hip/hip_runtime.h>
#include <hip/hip_bf16.h>

#define N_FEAT 128
#define HID 16
#define NCLS 10
#define NGRAPH 1024
#define SHIFT 7            // 128 nodes per bin
#define NBMAX 1024         // supports n <= 131072
#define CAP 24576          // LDS staging entries in k_place (96 KB)
#define CH 16384           // edges per k_bin block

__device__ __forceinline__ float u2f(unsigned int u) {
    union { unsigned int u; float f; } c; c.u = u; return c.f;
}
__device__ __forceinline__ float bf2f(__hip_bfloat16 b) {
    return __bfloat162float(b);
}
__device__ __forceinline__ float ldw(const void* __restrict__ p, int i, int isbf) {
    return isbf ? bf2f(((const __hip_bfloat16*)p)[i]) : ((const float*)p)[i];
}

// ---------------------------------------------------------------------------
// K0: runtime dtype probes (kept — these made R3 pass).
__global__ void k_detect(const int* __restrict__ ei,
                         const unsigned int* __restrict__ xw,
                         int* __restrict__ flags) {
    if (blockIdx.x == 0 && threadIdx.x == 0) {
        int nz = 0;
        for (int i = 1; i < 256; i += 2) nz |= ei[i];
        flags[0] = (nz == 0) ? 1 : 0;
        int cnt = 0;
        for (int i = 0; i < 64; i++) {
            unsigned int ef = xw[i] & 0x7F80u;
            if (ef >= 0x3C00u && ef <= 0x4080u) cnt++;
        }
        flags[1] = (cnt >= 32) ? 1 : 0;
    }
}

__global__ void k_zero_int(int* __restrict__ p, int n) {
    int i = blockIdx.x * blockDim.x + threadIdx.x;
    if (i < n) p[i] = 0;
}

// ---------------------------------------------------------------------------
// K1: h0[i] = emb[argmax(x[i,:])] — one 64-lane wave per node.
__global__ void k_argmax_embed(const void* __restrict__ x,
                               const void* __restrict__ emb,
                               const int* __restrict__ flags,
                               float* __restrict__ h, int n) {
    int wave = (int)((blockIdx.x * (unsigned)blockDim.x + threadIdx.x) >> 6);
    int lane = threadIdx.x & 63;
    if (wave >= n) return;
    int isbf = flags[1];
    float v0, v1;
    if (isbf) {
        const unsigned int* row =
            (const unsigned int*)((const __hip_bfloat16*)x + (size_t)wave * N_FEAT);
        unsigned int u = row[lane];
        v0 = u2f(u << 16);
        v1 = u2f(u & 0xffff0000u);
    } else {
        const float2* row = (const float2*)((const float*)x + (size_t)wave * N_FEAT);
        float2 u = row[lane];
        v0 = u.x; v1 = u.y;
    }
    float bv; int bi;
    if (v1 > v0) { bv = v1; bi = 2 * lane + 1; }
    else         { bv = v0; bi = 2 * lane; }
    #pragma unroll
    for (int off = 1; off < 64; off <<= 1) {
        float ov = __shfl_xor(bv, off);
        int   oi = __shfl_xor(bi, off);
        if (ov > bv || (ov == bv && oi < bi)) { bv = ov; bi = oi; }
    }
    if (lane < HID)
        h[(size_t)wave * HID + lane] = ldw(emb, bi * HID + lane, isbf);
}

// ---------------------------------------------------------------------------
// K2a: in-degree counts — fire-and-forget atomics (measured ~free in R3/R4).
__global__ void k_count(const int* __restrict__ ei, const int* __restrict__ flags,
                        int* __restrict__ dega, int e) {
    int i = blockIdx.x * blockDim.x + threadIdx.x;
    if (i >= e) return;
    int sh = flags[0];
    int d = ei[((size_t)(e + i)) << sh];
    atomicAdd(&dega[d], 1);
}

// K2b: exclusive scan dega -> rowStart (rowStart preserved for all later use).
__global__ void k_scan(const int* __restrict__ dega, int* __restrict__ rowStart, int n) {
    __shared__ int ls[1024];
    int t = threadIdx.x;
    int chunk = (n + 1023) >> 10;
    int s0 = t * chunk;
    int s1 = min(n, s0 + chunk);
    int sum = 0;
    for (int i = s0; i < s1; i++) sum += dega[i];
    ls[t] = sum;
    __syncthreads();
    #pragma unroll
    for (int off = 1; off < 1024; off <<= 1) {
        int v = (t >= off) ? ls[t - off] : 0;
        __syncthreads();
        ls[t] += v;
        __syncthreads();
    }
    int run = ls[t] - sum;           // exclusive prefix
    for (int i = s0; i < s1; i++) {
        rowStart[i] = run;
        run += dega[i];
    }
}

// K2c: seed coarse-bin write cursors from rowStart.
__global__ void k_seed(const int* __restrict__ rowStart, int* __restrict__ binPos,
                       int nbins) {
    int b = blockIdx.x * blockDim.x + threadIdx.x;
    if (b < nbins) binPos[b] = rowStart[b << SHIFT];
}

// K2d: coarse binning. Block handles CH edges; LDS histogram; ONE returning
// atomic per (block, nonempty bin) reserves a contiguous run; packed
// (src<<SHIFT | dstLow) written in ~bin-contiguous bursts.
__global__ void k_bin(const int* __restrict__ ei, const int* __restrict__ flags,
                      int* __restrict__ binPos, int* __restrict__ ebuf,
                      int e, int nbins) {
    __shared__ int lh[NBMAX], rb[NBMAX], rc[NBMAX];
    int t = threadIdx.x;
    for (int b = t; b < nbins; b += 256) { lh[b] = 0; rc[b] = 0; }
    __syncthreads();
    int base = blockIdx.x * CH;
    int sh = flags[0];
    for (int j = 0; j < CH / 256; j++) {
        int i = base + j * 256 + t;
        if (i < e) {
            int d = ei[((size_t)(e + i)) << sh];
            atomicAdd(&lh[d >> SHIFT], 1);
        }
    }
    __syncthreads();
    for (int b = t; b < nbins; b += 256) {
        int c = lh[b];
        rb[b] = c ? atomicAdd(&binPos[b], c) : 0;
    }
    __syncthreads();
    for (int j = 0; j < CH / 256; j++) {
        int i = base + j * 256 + t;
        if (i < e) {
            int s = ei[((size_t)i) << sh];
            int d = ei[((size_t)(e + i)) << sh];
            int bin = d >> SHIFT;
            int r = atomicAdd(&rc[bin], 1);
            ebuf[rb[bin] + r] = (s << SHIFT) | (d & ((1 << SHIFT) - 1));
        }
    }
}

// K2e: fine placement. One block per bin: stage bin's edges in LDS (reads all
// before any write -> in-place over the same buffer is safe), then place each
// src at rowStart[node] + rank. All traffic localized to one bin (~32 KB).
__global__ void k_place(int* __restrict__ col, const int* __restrict__ rowStart,
                        int n, int e) {
    __shared__ int stage[CAP];
    __shared__ int rc[1 << SHIFT];
    __shared__ int rs[1 << SHIFT];
    int b = blockIdx.x;
    int t = threadIdx.x;
    int nb = b << SHIFT;
    int s0 = rowStart[nb];
    int nend = nb + (1 << SHIFT);
    int s1 = (nend < n) ? rowStart[nend] : e;
    int cnt = s1 - s0;
    if (t < (1 << SHIFT)) {
        rc[t] = 0;
        int node = nb + t;
        rs[t] = (node < n) ? rowStart[node] : e;
    }
    bool st = (cnt <= CAP);
    if (st) for (int i = t; i < cnt; i += 256) stage[i] = col[s0 + i];
    __syncthreads();
    for (int i = t; i < cnt; i += 256) {
        int v = st ? stage[i] : col[s0 + i];
        int dl = v & ((1 << SHIFT) - 1);
        int r = atomicAdd(&rc[dl], 1);
        col[rs[dl] + r] = v >> SHIFT;
    }
}

// ---------------------------------------------------------------------------
// K3: fused gather + combine, layers 1/2 — float4 lanes (4 lanes per edge).
// lane: q=lane&3 (float4 slot), sg=lane>>2 (16 edge walkers per wave).
__global__ void k_gc(const int* __restrict__ col, const int* __restrict__ rowStart,
                     const float* __restrict__ hin,
                     const void* __restrict__ Wl, const void* __restrict__ bia,
                     const void* __restrict__ Wr, const int* __restrict__ flags,
                     float* __restrict__ hout, int n, int e) {
    __shared__ float wl[HID][HID + 1], wr[HID][HID + 1], bb[HID];
    int t = threadIdx.x;
    int isbf = flags[1];
    if (t < HID * HID) {
        wl[t >> 4][t & 15] = ldw(Wl, t, isbf);
        wr[t >> 4][t & 15] = ldw(Wr, t, isbf);
    }
    if (t < HID) bb[t] = ldw(bia, t, isbf);
    __syncthreads();
    int node = blockIdx.x * 4 + (t >> 6);
    if (node >= n) return;
    int lane = t & 63;
    int q = lane & 3;
    int sg = lane >> 2;
    int lo = rowStart[node];
    int hi = (node + 1 < n) ? rowStart[node + 1] : e;
    const float4* h4 = (const float4*)hin;
    float4 acc = make_float4(0.f, 0.f, 0.f, 0.f);
    for (int i = lo + sg; i < hi; i += 16) {
        int s = col[i];
        float4 v = h4[(size_t)s * 4 + q];
        acc.x += v.x; acc.y += v.y; acc.z += v.z; acc.w += v.w;
    }
    #pragma unroll
    for (int d = 4; d < 64; d <<= 1) {
        acc.x += __shfl_xor(acc.x, d);
        acc.y += __shfl_xor(acc.y, d);
        acc.z += __shfl_xor(acc.z, d);
        acc.w += __shfl_xor(acc.w, d);
    }
    float inv = 1.0f / fmaxf((float)(hi - lo), 1.0f);
    float a4[4] = {acc.x * inv, acc.y * inv, acc.z * inv, acc.w * inv};
    float4 hbv = h4[(size_t)node * 4 + q];
    float hb4[4] = {hbv.x, hbv.y, hbv.z, hbv.w};
    int f = lane & 15;
    float o = bb[f];
    #pragma unroll
    for (int k = 0; k < HID; k++) {
        float ak = __shfl(a4[k & 3], k >> 2);
        float hk = __shfl(hb4[k & 3], k >> 2);
        o += ak * wl[f][k] + hk * wr[f][k];
    }
    float sq = o * o;
    #pragma unroll
    for (int d = 1; d < 16; d <<= 1) sq += __shfl_xor(sq, d);
    float innorm = 1.0f / fmaxf(sqrtf(sq), 1e-12f);
    o = fmaxf(o * innorm, 0.0f);
    if (lane < HID) hout[(size_t)node * HID + lane] = o;
}

// K4: layer-3 variant (10 outputs, zero-padded weight rows, no ReLU).
__global__ void k_gc3(const int* __restrict__ col, const int* __restrict__ rowStart,
                      const float* __restrict__ hin,
                      const void* __restrict__ Wl, const void* __restrict__ bia,
                      const void* __restrict__ Wr, const int* __restrict__ flags,
                      float* __restrict__ h3, int n, int e) {
    __shared__ float wl[HID][HID + 1], wr[HID][HID + 1], bb[HID];
    int t = threadIdx.x;
    int isbf = flags[1];
    if (t < HID * HID) {
        int r = t >> 4, c = t & 15;
        wl[r][c] = (r < NCLS) ? ldw(Wl, r * HID + c, isbf) : 0.0f;
        wr[r][c] = (r < NCLS) ? ldw(Wr, r * HID + c, isbf) : 0.0f;
    }
    if (t < HID) bb[t] = (t < NCLS) ? ldw(bia, t, isbf) : 0.0f;
    __syncthreads();
    int node = blockIdx.x * 4 + (t >> 6);
    if (node >= n) return;
    int lane = t & 63;
    int q = lane & 3;
    int sg = lane >> 2;
    int lo = rowStart[node];
    int hi = (node + 1 < n) ? rowStart[node + 1] : e;
    const float4* h4 = (const float4*)hin;
    float4 acc = make_float4(0.f, 0.f, 0.f, 0.f);
    for (int i = lo + sg; i < hi; i += 16) {
        int s = col[i];
        float4 v = h4[(size_t)s * 4 + q];
        acc.x += v.x; acc.y += v.y; acc.z += v.z; acc.w += v.w;
    }
    #pragma unroll
    for (int d = 4; d < 64; d <<= 1) {
        acc.x += __shfl_xor(acc.x, d);
        acc.y += __shfl_xor(acc.y, d);
        acc.z += __shfl_xor(acc.z, d);
        acc.w += __shfl_xor(acc.w, d);
    }
    float inv = 1.0f / fmaxf((float)(hi - lo), 1.0f);
    float a4[4] = {acc.x * inv, acc.y * inv, acc.z * inv, acc.w * inv};
    float4 hbv = h4[(size_t)node * 4 + q];
    float hb4[4] = {hbv.x, hbv.y, hbv.z, hbv.w};
    int f = lane & 15;
    float o = bb[f];
    #pragma unroll
    for (int k = 0; k < HID; k++) {
        float ak = __shfl(a4[k & 3], k >> 2);
        float hk = __shfl(hb4[k & 3], k >> 2);
        o += ak * wl[f][k] + hk * wr[f][k];
    }
    float sq = o * o;              // rows >= NCLS contribute 0
    #pragma unroll
    for (int d = 1; d < 16; d <<= 1) sq += __shfl_xor(sq, d);
    float innorm = 1.0f / fmaxf(sqrtf(sq), 1e-12f);
    o = o * innorm;
    if (lane < NCLS) h3[(size_t)node * NCLS + lane] = o;
}

// ---------------------------------------------------------------------------
// K5: per-graph mean pool (batch sorted -> binary search) + softmax.
__device__ __forceinline__ int lbound(const int* __restrict__ a, int n, int key, int sh) {
    int lo = 0, hi = n;
    while (lo < hi) {
        int mid = (lo + hi) >> 1;
        if (a[((size_t)mid) << sh] < key) lo = mid + 1; else hi = mid;
    }
    return lo;
}

__global__ void k_pool_softmax(const float* __restrict__ h3,
                               const int* __restrict__ batch,
                               const int* __restrict__ flags,
                               void* __restrict__ out, int n) {
    int g = blockIdx.x;
    int lane = threadIdx.x;
    int sh = flags[0];
    int lo = lbound(batch, n, g, sh);
    int hi = lbound(batch, n, g + 1, sh);
    float acc[NCLS];
    #pragma unroll
    for (int c = 0; c < NCLS; c++) acc[c] = 0.0f;
    for (int i = lo + lane; i < hi; i += 64) {
        const float* r = h3 + (size_t)i * NCLS;
        #pragma unroll
        for (int c = 0; c < NCLS; c++) acc[c] += r[c];
    }
    #pragma unroll
    for (int c = 0; c < NCLS; c++) {
        #pragma unroll
        for (int off = 1; off < 64; off <<= 1)
            acc[c] += __shfl_xor(acc[c], off);
    }
    float invc = 1.0f / fmaxf((float)(hi - lo), 1.0f);
    float m = -1e30f;
    #pragma unroll
    for (int c = 0; c < NCLS; c++) { acc[c] *= invc; m = fmaxf(m, acc[c]); }
    float s = 0.0f;
    #pragma unroll
    for (int c = 0; c < NCLS; c++) { acc[c] = expf(acc[c] - m); s += acc[c]; }
    float invs = 1.0f / s;
    if (lane < NCLS) {
        float v = acc[lane] * invs;
        size_t idx = (size_t)g * NCLS + lane;
        if (flags[1]) ((__hip_bfloat16*)out)[idx] = __float2bfloat16(v);
        else          ((float*)out)[idx] = v;
    }
}

// ---------------------------------------------------------------------------
extern "C" void kernel_launch(void* const* d_in, const int* in_sizes, int n_in,
                              void* d_out, int out_size, void* d_ws, size_t ws_size,
                              hipStream_t stream) {
    const void* x   = d_in[0];
    const int*  ei  = (const int*)d_in[1];
    const int*  bat = (const int*)d_in[2];
    const void* emb = d_in[3];
    const void* W1l = d_in[4];  const void* b1 = d_in[5];  const void* W1r = d_in[6];
    const void* W2l = d_in[7];  const void* b2 = d_in[8];  const void* W2r = d_in[9];
    const void* W3l = d_in[10]; const void* b3 = d_in[11]; const void* W3r = d_in[12];

    int n = in_sizes[0] / N_FEAT;
    int e = in_sizes[1] / 2;
    int nbins = (n + (1 << SHIFT) - 1) >> SHIFT;

    // ws: hcur[16n] f | hnext[16n] f (h3 aliased) | col[e] | rowStart[n] |
    //     dega[n] | binPos[nbins] | flags[2]   (~39 MB)
    float* hcur     = (float*)d_ws;
    float* hnext    = hcur + (size_t)n * HID;
    int*   col      = (int*)(hnext + (size_t)n * HID);
    int*   rowStart = col + e;
    int*   dega     = rowStart + n;
    int*   binPos   = dega + n;
    int*   flags    = binPos + nbins;
    float* h3       = hnext;

    int egrid  = (e + 255) / 256;
    int ngrid4 = (n + 3) / 4;
    int nblk   = (e + CH - 1) / CH;

    // probes + CSR build (counts -> scan -> seed -> coarse bin -> fine place)
    k_detect<<<1, 64, 0, stream>>>(ei, (const unsigned int*)x, flags);
    k_zero_int<<<(n + 255) / 256, 256, 0, stream>>>(dega, n);
    k_count<<<egrid, 256, 0, stream>>>(ei, flags, dega, e);
    k_scan<<<1, 1024, 0, stream>>>(dega, rowStart, n);
    k_seed<<<(nbins + 255) / 256, 256, 0, stream>>>(rowStart, binPos, nbins);
    k_bin<<<nblk, 256, 0, stream>>>(ei, flags, binPos, col, e, nbins);
    k_place<<<nbins, 256, 0, stream>>>(col, rowStart, n, e);

    // initial embedding
    k_argmax_embed<<<ngrid4, 256, 0, stream>>>(x, emb, flags, hcur, n);

    // 3 fused gather+combine layers
    k_gc <<<ngrid4, 256, 0, stream>>>(col, rowStart, hcur,  W1l, b1, W1r, flags, hnext, n, e);
    k_gc <<<ngrid4, 256, 0, stream>>>(col, rowStart, hnext, W2l, b2, W2r, flags, hcur,  n, e);
    k_gc3<<<ngrid4, 256, 0, stream>>>(col, rowStart, hcur,  W3l, b3, W3r, flags, h3,    n, e);

    // pool + softmax
    k_pool_softmax<<<NGRAPH, 64, 0, stream>>>(h3, bat, flags, d_out, n);
}

// Round 6
// 706.477 us; speedup vs baseline: 2.1789x; 1.5281x over previous
//
#include <hip/hip_runtime.h>
#include <hip/hip_bf16.h>

#define N_FEAT 128
#define HID 16
#define NCLS 10
#define NGRAPH 1024
#define SHIFT 7            // 128 nodes per coarse bin
#define NBMAX 1024         // supports n <= 131072
#define CAP 24576          // LDS staging entries in k_place (96 KB)
#define CH 16384           // edges per binning block

__device__ __forceinline__ float u2f(unsigned int u) {
    union { unsigned int u; float f; } c; c.u = u; return c.f;
}
__device__ __forceinline__ float bf2f(__hip_bfloat16 b) {
    return __bfloat162float(b);
}
__device__ __forceinline__ float ldw(const void* __restrict__ p, int i, int isbf) {
    return isbf ? bf2f(((const __hip_bfloat16*)p)[i]) : ((const float*)p)[i];
}

// ---------------------------------------------------------------------------
// K0: runtime dtype probes (kept — these made R3 pass).
__global__ void k_detect(const int* __restrict__ ei,
                         const unsigned int* __restrict__ xw,
                         int* __restrict__ flags) {
    if (blockIdx.x == 0 && threadIdx.x == 0) {
        int nz = 0;
        for (int i = 1; i < 256; i += 2) nz |= ei[i];
        flags[0] = (nz == 0) ? 1 : 0;
        int cnt = 0;
        for (int i = 0; i < 64; i++) {
            unsigned int ef = xw[i] & 0x7F80u;
            if (ef >= 0x3C00u && ef <= 0x4080u) cnt++;
        }
        flags[1] = (cnt >= 32) ? 1 : 0;
    }
}

__global__ void k_zero_int(int* __restrict__ p, int n) {
    int i = blockIdx.x * blockDim.x + threadIdx.x;
    if (i < n) p[i] = 0;
}

// ---------------------------------------------------------------------------
// K1: h0[i] = emb[argmax(x[i,:])] — one 64-lane wave per node.
__global__ void k_argmax_embed(const void* __restrict__ x,
                               const void* __restrict__ emb,
                               const int* __restrict__ flags,
                               float* __restrict__ h, int n) {
    int wave = (int)((blockIdx.x * (unsigned)blockDim.x + threadIdx.x) >> 6);
    int lane = threadIdx.x & 63;
    if (wave >= n) return;
    int isbf = flags[1];
    float v0, v1;
    if (isbf) {
        const unsigned int* row =
            (const unsigned int*)((const __hip_bfloat16*)x + (size_t)wave * N_FEAT);
        unsigned int u = row[lane];
        v0 = u2f(u << 16);
        v1 = u2f(u & 0xffff0000u);
    } else {
        const float2* row = (const float2*)((const float*)x + (size_t)wave * N_FEAT);
        float2 u = row[lane];
        v0 = u.x; v1 = u.y;
    }
    float bv; int bi;
    if (v1 > v0) { bv = v1; bi = 2 * lane + 1; }
    else         { bv = v0; bi = 2 * lane; }
    #pragma unroll
    for (int off = 1; off < 64; off <<= 1) {
        float ov = __shfl_xor(bv, off);
        int   oi = __shfl_xor(bi, off);
        if (ov > bv || (ov == bv && oi < bi)) { bv = ov; bi = oi; }
    }
    if (lane < HID)
        h[(size_t)wave * HID + lane] = ldw(emb, bi * HID + lane, isbf);
}

// ---------------------------------------------------------------------------
// K2a: per-block LDS bin histogram; ONE returning global atomic per
// (block, nonempty bin) reserves a run in binCnt; offsets stashed in rbBuf.
// Replaces the 6.4M-atomic k_count (254 us, 200 MB fabric writes in R5).
__global__ void k_binhist(const int* __restrict__ ei, const int* __restrict__ flags,
                          int* __restrict__ binCnt, int* __restrict__ rbBuf,
                          int e, int nbins) {
    __shared__ int lh[NBMAX];
    int t = threadIdx.x;
    for (int b = t; b < nbins; b += 256) lh[b] = 0;
    __syncthreads();
    int base = blockIdx.x * CH;
    int sh = flags[0];
    for (int j = 0; j < CH / 256; j++) {
        int i = base + j * 256 + t;
        if (i < e) {
            int d = ei[((size_t)(e + i)) << sh];
            atomicAdd(&lh[d >> SHIFT], 1);
        }
    }
    __syncthreads();
    int* rb = rbBuf + (size_t)blockIdx.x * nbins;
    for (int b = t; b < nbins; b += 256) {
        int c = lh[b];
        rb[b] = c ? atomicAdd(&binCnt[b], c) : 0;
    }
}

// K2b: exclusive scan of binCnt[0..nbins) -> binStart; binStart[nbins] = e.
__global__ void k_scanbins(const int* __restrict__ binCnt,
                           int* __restrict__ binStart, int nbins, int e) {
    __shared__ int ls[1024];
    int t = threadIdx.x;
    int v = (t < nbins) ? binCnt[t] : 0;
    ls[t] = v;
    __syncthreads();
    #pragma unroll
    for (int off = 1; off < 1024; off <<= 1) {
        int w = (t >= off) ? ls[t - off] : 0;
        __syncthreads();
        ls[t] += w;
        __syncthreads();
    }
    if (t < nbins) binStart[t] = ls[t] - v;   // exclusive
    if (t == 0) binStart[nbins] = e;
}

// K2c: placement into coarse bins using precomputed per-(block,bin) offsets.
// No global returning atomics; LDS rank cursors only.
__global__ void k_binplace(const int* __restrict__ ei, const int* __restrict__ flags,
                           const int* __restrict__ binStart,
                           const int* __restrict__ rbBuf,
                           int* __restrict__ col, int e, int nbins) {
    __shared__ int bs[NBMAX], rc[NBMAX];
    int t = threadIdx.x;
    const int* rb = rbBuf + (size_t)blockIdx.x * nbins;
    for (int b = t; b < nbins; b += 256) {
        bs[b] = binStart[b] + rb[b];
        rc[b] = 0;
    }
    __syncthreads();
    int base = blockIdx.x * CH;
    int sh = flags[0];
    for (int j = 0; j < CH / 256; j++) {
        int i = base + j * 256 + t;
        if (i < e) {
            int s = ei[((size_t)i) << sh];
            int d = ei[((size_t)(e + i)) << sh];
            int bin = d >> SHIFT;
            int r = atomicAdd(&rc[bin], 1);
            col[bs[bin] + r] = (s << SHIFT) | (d & ((1 << SHIFT) - 1));
        }
    }
}

// K2d: fine placement + per-node rowStart. One block per bin: stage edges in
// LDS, 128-counter histogram, 128-wide scan -> rowStart; place srcs in order.
__global__ void k_place(int* __restrict__ col, const int* __restrict__ binStart,
                        int* __restrict__ rowStart, int n, int e) {
    __shared__ int stage[CAP];
    __shared__ int cntN[1 << SHIFT];
    __shared__ int sc[1 << SHIFT];
    __shared__ int rs[1 << SHIFT];
    int b = blockIdx.x;
    int t = threadIdx.x;
    int nb = b << SHIFT;
    int s0 = binStart[b];
    int s1 = binStart[b + 1];
    int cnt = s1 - s0;
    if (t < (1 << SHIFT)) cntN[t] = 0;
    bool st = (cnt <= CAP);
    __syncthreads();
    for (int i = t; i < cnt; i += 256) {
        int v = col[s0 + i];
        if (st) stage[i] = v;
        atomicAdd(&cntN[v & ((1 << SHIFT) - 1)], 1);
    }
    __syncthreads();
    if (t < (1 << SHIFT)) sc[t] = cntN[t];
    __syncthreads();
    #pragma unroll
    for (int off = 1; off < (1 << SHIFT); off <<= 1) {
        int w = 0;
        if (t < (1 << SHIFT) && t >= off) w = sc[t - off];
        __syncthreads();
        if (t < (1 << SHIFT)) sc[t] += w;
        __syncthreads();
    }
    if (t < (1 << SHIFT)) {
        int start = s0 + sc[t] - cntN[t];     // exclusive prefix
        rs[t] = start;
        int node = nb + t;
        if (node < n) rowStart[node] = start;
        cntN[t] = 0;                           // reuse as rank cursor
    }
    __syncthreads();
    for (int i = t; i < cnt; i += 256) {
        int v = st ? stage[i] : col[s0 + i];
        int dl = v & ((1 << SHIFT) - 1);
        int r = atomicAdd(&cntN[dl], 1);
        col[rs[dl] + r] = v >> SHIFT;
    }
}

// ---------------------------------------------------------------------------
// K3: fused gather + combine, layers 1/2 — float4 lanes (4 lanes per edge).
__global__ void k_gc(const int* __restrict__ col, const int* __restrict__ rowStart,
                     const float* __restrict__ hin,
                     const void* __restrict__ Wl, const void* __restrict__ bia,
                     const void* __restrict__ Wr, const int* __restrict__ flags,
                     float* __restrict__ hout, int n, int e) {
    __shared__ float wl[HID][HID + 1], wr[HID][HID + 1], bb[HID];
    int t = threadIdx.x;
    int isbf = flags[1];
    if (t < HID * HID) {
        wl[t >> 4][t & 15] = ldw(Wl, t, isbf);
        wr[t >> 4][t & 15] = ldw(Wr, t, isbf);
    }
    if (t < HID) bb[t] = ldw(bia, t, isbf);
    __syncthreads();
    int node = blockIdx.x * 4 + (t >> 6);
    if (node >= n) return;
    int lane = t & 63;
    int q = lane & 3;
    int sg = lane >> 2;
    int lo = rowStart[node];
    int hi = (node + 1 < n) ? rowStart[node + 1] : e;
    const float4* h4 = (const float4*)hin;
    float4 acc = make_float4(0.f, 0.f, 0.f, 0.f);
    for (int i = lo + sg; i < hi; i += 16) {
        int s = col[i];
        float4 v = h4[(size_t)s * 4 + q];
        acc.x += v.x; acc.y += v.y; acc.z += v.z; acc.w += v.w;
    }
    #pragma unroll
    for (int d = 4; d < 64; d <<= 1) {
        acc.x += __shfl_xor(acc.x, d);
        acc.y += __shfl_xor(acc.y, d);
        acc.z += __shfl_xor(acc.z, d);
        acc.w += __shfl_xor(acc.w, d);
    }
    float inv = 1.0f / fmaxf((float)(hi - lo), 1.0f);
    float a4[4] = {acc.x * inv, acc.y * inv, acc.z * inv, acc.w * inv};
    float4 hbv = h4[(size_t)node * 4 + q];
    float hb4[4] = {hbv.x, hbv.y, hbv.z, hbv.w};
    int f = lane & 15;
    float o = bb[f];
    #pragma unroll
    for (int k = 0; k < HID; k++) {
        float ak = __shfl(a4[k & 3], k >> 2);
        float hk = __shfl(hb4[k & 3], k >> 2);
        o += ak * wl[f][k] + hk * wr[f][k];
    }
    float sq = o * o;
    #pragma unroll
    for (int d = 1; d < 16; d <<= 1) sq += __shfl_xor(sq, d);
    float innorm = 1.0f / fmaxf(sqrtf(sq), 1e-12f);
    o = fmaxf(o * innorm, 0.0f);
    if (lane < HID) hout[(size_t)node * HID + lane] = o;
}

// K4: layer-3 variant (10 outputs, zero-padded weight rows, no ReLU).
__global__ void k_gc3(const int* __restrict__ col, const int* __restrict__ rowStart,
                      const float* __restrict__ hin,
                      const void* __restrict__ Wl, const void* __restrict__ bia,
                      const void* __restrict__ Wr, const int* __restrict__ flags,
                      float* __restrict__ h3, int n, int e) {
    __shared__ float wl[HID][HID + 1], wr[HID][HID + 1], bb[HID];
    int t = threadIdx.x;
    int isbf = flags[1];
    if (t < HID * HID) {
        int r = t >> 4, c = t & 15;
        wl[r][c] = (r < NCLS) ? ldw(Wl, r * HID + c, isbf) : 0.0f;
        wr[r][c] = (r < NCLS) ? ldw(Wr, r * HID + c, isbf) : 0.0f;
    }
    if (t < HID) bb[t] = (t < NCLS) ? ldw(bia, t, isbf) : 0.0f;
    __syncthreads();
    int node = blockIdx.x * 4 + (t >> 6);
    if (node >= n) return;
    int lane = t & 63;
    int q = lane & 3;
    int sg = lane >> 2;
    int lo = rowStart[node];
    int hi = (node + 1 < n) ? rowStart[node + 1] : e;
    const float4* h4 = (const float4*)hin;
    float4 acc = make_float4(0.f, 0.f, 0.f, 0.f);
    for (int i = lo + sg; i < hi; i += 16) {
        int s = col[i];
        float4 v = h4[(size_t)s * 4 + q];
        acc.x += v.x; acc.y += v.y; acc.z += v.z; acc.w += v.w;
    }
    #pragma unroll
    for (int d = 4; d < 64; d <<= 1) {
        acc.x += __shfl_xor(acc.x, d);
        acc.y += __shfl_xor(acc.y, d);
        acc.z += __shfl_xor(acc.z, d);
        acc.w += __shfl_xor(acc.w, d);
    }
    float inv = 1.0f / fmaxf((float)(hi - lo), 1.0f);
    float a4[4] = {acc.x * inv, acc.y * inv, acc.z * inv, acc.w * inv};
    float4 hbv = h4[(size_t)node * 4 + q];
    float hb4[4] = {hbv.x, hbv.y, hbv.z, hbv.w};
    int f = lane & 15;
    float o = bb[f];
    #pragma unroll
    for (int k = 0; k < HID; k++) {
        float ak = __shfl(a4[k & 3], k >> 2);
        float hk = __shfl(hb4[k & 3], k >> 2);
        o += ak * wl[f][k] + hk * wr[f][k];
    }
    float sq = o * o;
    #pragma unroll
    for (int d = 1; d < 16; d <<= 1) sq += __shfl_xor(sq, d);
    float innorm = 1.0f / fmaxf(sqrtf(sq), 1e-12f);
    o = o * innorm;
    if (lane < NCLS) h3[(size_t)node * NCLS + lane] = o;
}

// ---------------------------------------------------------------------------
// K5: per-graph mean pool (batch sorted -> binary search) + softmax.
__device__ __forceinline__ int lbound(const int* __restrict__ a, int n, int key, int sh) {
    int lo = 0, hi = n;
    while (lo < hi) {
        int mid = (lo + hi) >> 1;
        if (a[((size_t)mid) << sh] < key) lo = mid + 1; else hi = mid;
    }
    return lo;
}

__global__ void k_pool_softmax(const float* __restrict__ h3,
                               const int* __restrict__ batch,
                               const int* __restrict__ flags,
                               void* __restrict__ out, int n) {
    int g = blockIdx.x;
    int lane = threadIdx.x;
    int sh = flags[0];
    int lo = lbound(batch, n, g, sh);
    int hi = lbound(batch, n, g + 1, sh);
    float acc[NCLS];
    #pragma unroll
    for (int c = 0; c < NCLS; c++) acc[c] = 0.0f;
    for (int i = lo + lane; i < hi; i += 64) {
        const float* r = h3 + (size_t)i * NCLS;
        #pragma unroll
        for (int c = 0; c < NCLS; c++) acc[c] += r[c];
    }
    #pragma unroll
    for (int c = 0; c < NCLS; c++) {
        #pragma unroll
        for (int off = 1; off < 64; off <<= 1)
            acc[c] += __shfl_xor(acc[c], off);
    }
    float invc = 1.0f / fmaxf((float)(hi - lo), 1.0f);
    float m = -1e30f;
    #pragma unroll
    for (int c = 0; c < NCLS; c++) { acc[c] *= invc; m = fmaxf(m, acc[c]); }
    float s = 0.0f;
    #pragma unroll
    for (int c = 0; c < NCLS; c++) { acc[c] = expf(acc[c] - m); s += acc[c]; }
    float invs = 1.0f / s;
    if (lane < NCLS) {
        float v = acc[lane] * invs;
        size_t idx = (size_t)g * NCLS + lane;
        if (flags[1]) ((__hip_bfloat16*)out)[idx] = __float2bfloat16(v);
        else          ((float*)out)[idx] = v;
    }
}

// ---------------------------------------------------------------------------
extern "C" void kernel_launch(void* const* d_in, const int* in_sizes, int n_in,
                              void* d_out, int out_size, void* d_ws, size_t ws_size,
                              hipStream_t stream) {
    const void* x   = d_in[0];
    const int*  ei  = (const int*)d_in[1];
    const int*  bat = (const int*)d_in[2];
    const void* emb = d_in[3];
    const void* W1l = d_in[4];  const void* b1 = d_in[5];  const void* W1r = d_in[6];
    const void* W2l = d_in[7];  const void* b2 = d_in[8];  const void* W2r = d_in[9];
    const void* W3l = d_in[10]; const void* b3 = d_in[11]; const void* W3r = d_in[12];

    int n = in_sizes[0] / N_FEAT;
    int e = in_sizes[1] / 2;
    int nbins = (n + (1 << SHIFT) - 1) >> SHIFT;
    int nblk  = (e + CH - 1) / CH;

    // ws: hcur[16n] f | hnext[16n] f (h3 aliased) | col[e] | rowStart[n] |
    //     binCnt[nbins] | binStart[nbins+1] | rbBuf[nblk*nbins] | flags[2]
    float* hcur     = (float*)d_ws;
    float* hnext    = hcur + (size_t)n * HID;
    int*   col      = (int*)(hnext + (size_t)n * HID);
    int*   rowStart = col + e;
    int*   binCnt   = rowStart + n;
    int*   binStart = binCnt + nbins;
    int*   rbBuf    = binStart + (nbins + 1);
    int*   flags    = rbBuf + (size_t)nblk * nbins;
    float* h3       = hnext;

    int ngrid4 = (n + 3) / 4;

    // probes + CSR build (hist+reserve -> scan -> place coarse -> place fine)
    k_detect<<<1, 64, 0, stream>>>(ei, (const unsigned int*)x, flags);
    k_zero_int<<<(nbins + 255) / 256, 256, 0, stream>>>(binCnt, nbins);
    k_binhist<<<nblk, 256, 0, stream>>>(ei, flags, binCnt, rbBuf, e, nbins);
    k_scanbins<<<1, 1024, 0, stream>>>(binCnt, binStart, nbins, e);
    k_binplace<<<nblk, 256, 0, stream>>>(ei, flags, binStart, rbBuf, col, e, nbins);
    k_place<<<nbins, 256, 0, stream>>>(col, binStart, rowStart, n, e);

    // initial embedding
    k_argmax_embed<<<ngrid4, 256, 0, stream>>>(x, emb, flags, hcur, n);

    // 3 fused gather+combine layers
    k_gc <<<ngrid4, 256, 0, stream>>>(col, rowStart, hcur,  W1l, b1, W1r, flags, hnext, n, e);
    k_gc <<<ngrid4, 256, 0, stream>>>(col, rowStart, hnext, W2l, b2, W2r, flags, hcur,  n, e);
    k_gc3<<<ngrid4, 256, 0, stream>>>(col, rowStart, hcur,  W3l, b3, W3r, flags, h3,    n, e);

    // pool + softmax
    k_pool_softmax<<<NGRAPH, 64, 0, stream>>>(h3, bat, flags, d_out, n);
}

// Round 7
// 634.577 us; speedup vs baseline: 2.4258x; 1.1133x over previous
//
#include <hip/hip_runtime.h>
#include <hip/hip_bf16.h>

#define N_FEAT 128
#define HID 16
#define NCLS 10
#define NGRAPH 1024
#define SHIFT 7            // 128 nodes per coarse bin
#define NBMAX 1024         // supports n <= 131072
#define CAP 24576          // LDS staging entries in k_place (96 KB)
#define CH 8192            // edges per binning block
#define EPB (CH / 256)     // edges per thread in binning kernels

__device__ __forceinline__ float u2f(unsigned int u) {
    union { unsigned int u; float f; } c; c.u = u; return c.f;
}
__device__ __forceinline__ float bf2f(__hip_bfloat16 b) {
    return __bfloat162float(b);
}
__device__ __forceinline__ float ldw(const void* __restrict__ p, int i, int isbf) {
    return isbf ? bf2f(((const __hip_bfloat16*)p)[i]) : ((const float*)p)[i];
}

// ---------------------------------------------------------------------------
// K0: runtime dtype probes (kept — these made R3 pass).
__global__ void k_detect(const int* __restrict__ ei,
                         const unsigned int* __restrict__ xw,
                         int* __restrict__ flags) {
    if (blockIdx.x == 0 && threadIdx.x == 0) {
        int nz = 0;
        for (int i = 1; i < 256; i += 2) nz |= ei[i];
        flags[0] = (nz == 0) ? 1 : 0;
        int cnt = 0;
        for (int i = 0; i < 64; i++) {
            unsigned int ef = xw[i] & 0x7F80u;
            if (ef >= 0x3C00u && ef <= 0x4080u) cnt++;
        }
        flags[1] = (cnt >= 32) ? 1 : 0;
    }
}

// ---------------------------------------------------------------------------
// K1: h0[i] = emb[argmax(x[i,:])] — one 64-lane wave per node.
__global__ void k_argmax_embed(const void* __restrict__ x,
                               const void* __restrict__ emb,
                               const int* __restrict__ flags,
                               float* __restrict__ h, int n) {
    int wave = (int)((blockIdx.x * (unsigned)blockDim.x + threadIdx.x) >> 6);
    int lane = threadIdx.x & 63;
    if (wave >= n) return;
    int isbf = flags[1];
    float v0, v1;
    if (isbf) {
        const unsigned int* row =
            (const unsigned int*)((const __hip_bfloat16*)x + (size_t)wave * N_FEAT);
        unsigned int u = row[lane];
        v0 = u2f(u << 16);
        v1 = u2f(u & 0xffff0000u);
    } else {
        const float2* row = (const float2*)((const float*)x + (size_t)wave * N_FEAT);
        float2 u = row[lane];
        v0 = u.x; v1 = u.y;
    }
    float bv; int bi;
    if (v1 > v0) { bv = v1; bi = 2 * lane + 1; }
    else         { bv = v0; bi = 2 * lane; }
    #pragma unroll
    for (int off = 1; off < 64; off <<= 1) {
        float ov = __shfl_xor(bv, off);
        int   oi = __shfl_xor(bi, off);
        if (ov > bv || (ov == bv && oi < bi)) { bv = ov; bi = oi; }
    }
    if (lane < HID)
        h[(size_t)wave * HID + lane] = ldw(emb, bi * HID + lane, isbf);
}

// ---------------------------------------------------------------------------
// K2a: per-block LDS bin histogram -> plain coalesced store of the count row.
// NO global atomics (R5/R6 showed returning/fabric atomics are the cost).
__global__ void k_binhist(const int* __restrict__ ei, const int* __restrict__ flags,
                          int* __restrict__ rbBuf, int e, int nbins) {
    __shared__ int lh[NBMAX];
    int t = threadIdx.x;
    for (int b = t; b < nbins; b += 256) lh[b] = 0;
    __syncthreads();
    int base = blockIdx.x * CH;
    int sh = flags[0];
    for (int j = 0; j < EPB; j++) {
        int i = base + j * 256 + t;
        if (i < e) {
            int d = ei[((size_t)(e + i)) << sh];
            atomicAdd(&lh[d >> SHIFT], 1);
        }
    }
    __syncthreads();
    int* row = rbBuf + (size_t)blockIdx.x * nbins;
    for (int b = t; b < nbins; b += 256) row[b] = lh[b];
}

// K2b: per-bin in-place exclusive scan over blocks: rbBuf[blk][bin] becomes
// the offset of block blk's run within bin; binCnt[bin] = total.
__global__ void k_colscan(int* __restrict__ rbBuf, int* __restrict__ binCnt,
                          int nblk, int nbins) {
    __shared__ int ls[1024];
    int b = blockIdx.x, t = threadIdx.x;
    int v = (t < nblk) ? rbBuf[(size_t)t * nbins + b] : 0;
    ls[t] = v;
    __syncthreads();
    #pragma unroll
    for (int off = 1; off < 1024; off <<= 1) {
        int w = (t >= off) ? ls[t - off] : 0;
        __syncthreads();
        ls[t] += w;
        __syncthreads();
    }
    if (t < nblk) rbBuf[(size_t)t * nbins + b] = ls[t] - v;  // exclusive
    if (t == 1023) binCnt[b] = ls[t];                        // total
}

// K2c: exclusive scan of binCnt[0..nbins) -> binStart; binStart[nbins] = e.
__global__ void k_scanbins(const int* __restrict__ binCnt,
                           int* __restrict__ binStart, int nbins, int e) {
    __shared__ int ls[1024];
    int t = threadIdx.x;
    int v = (t < nbins) ? binCnt[t] : 0;
    ls[t] = v;
    __syncthreads();
    #pragma unroll
    for (int off = 1; off < 1024; off <<= 1) {
        int w = (t >= off) ? ls[t - off] : 0;
        __syncthreads();
        ls[t] += w;
        __syncthreads();
    }
    if (t < nbins) binStart[t] = ls[t] - v;
    if (t == 0) binStart[nbins] = e;
}

// K2d: coarse placement, LDS-sorted for coalesced writes. Block stages its CH
// edges in LDS ordered by bin, then writes out linearly: consecutive threads
// hit consecutive addresses within each run (runs of adjacent blocks tile
// contiguously in col). No global atomics.
__global__ __launch_bounds__(256) void k_binplace(
        const int* __restrict__ ei, const int* __restrict__ flags,
        const int* __restrict__ binStart, const int* __restrict__ rbBuf,
        int* __restrict__ col, int e, int nbins) {
    __shared__ int cnt[NBMAX];
    __shared__ int ldsOff[NBMAX];
    __shared__ int ldsBase[NBMAX];
    __shared__ int ps[256];
    __shared__ int stage[CH];
    __shared__ unsigned short binOf[CH];
    int t = threadIdx.x;
    for (int b = t; b < nbins; b += 256) cnt[b] = 0;
    __syncthreads();
    int base = blockIdx.x * CH;
    int sh = flags[0];
    int myV[EPB]; short myB[EPB];
    for (int j = 0; j < EPB; j++) {
        int i = base + j * 256 + t;
        if (i < e) {
            int s = ei[((size_t)i) << sh];
            int d = ei[((size_t)(e + i)) << sh];
            myV[j] = (s << SHIFT) | (d & ((1 << SHIFT) - 1));
            int b2 = d >> SHIFT;
            myB[j] = (short)b2;
            atomicAdd(&cnt[b2], 1);
        } else myB[j] = -1;
    }
    __syncthreads();
    // exclusive scan of cnt[0..nbins) into ldsOff (4 bins per thread)
    int c[4]; int lsum = 0;
    int bb = t * 4;
    #pragma unroll
    for (int k = 0; k < 4; k++) {
        int b2 = bb + k;
        c[k] = (b2 < nbins) ? cnt[b2] : 0;
        lsum += c[k];
    }
    ps[t] = lsum;
    __syncthreads();
    #pragma unroll
    for (int off = 1; off < 256; off <<= 1) {
        int w = (t >= off) ? ps[t - off] : 0;
        __syncthreads();
        ps[t] += w;
        __syncthreads();
    }
    int run = ps[t] - lsum;
    #pragma unroll
    for (int k = 0; k < 4; k++) {
        int b2 = bb + k;
        if (b2 < nbins) ldsOff[b2] = run;
        run += c[k];
    }
    __syncthreads();
    const int* rb = rbBuf + (size_t)blockIdx.x * nbins;
    for (int b2 = t; b2 < nbins; b2 += 256) {
        ldsBase[b2] = binStart[b2] + rb[b2] - ldsOff[b2];
        cnt[b2] = 0;                               // reuse as rank cursor
    }
    __syncthreads();
    for (int j = 0; j < EPB; j++) {
        if (myB[j] >= 0) {
            int b2 = myB[j];
            int r = atomicAdd(&cnt[b2], 1);
            int p = ldsOff[b2] + r;
            stage[p] = myV[j];
            binOf[p] = (unsigned short)b2;
        }
    }
    __syncthreads();
    int total = e - base;
    if (total > CH) total = CH;
    for (int i = t; i < total; i += 256) {
        int b2 = binOf[i];
        col[ldsBase[b2] + i] = stage[i];
    }
}

// K2e: fine placement + per-node rowStart (unchanged from R6).
__global__ void k_place(int* __restrict__ col, const int* __restrict__ binStart,
                        int* __restrict__ rowStart, int n, int e) {
    __shared__ int stage[CAP];
    __shared__ int cntN[1 << SHIFT];
    __shared__ int sc[1 << SHIFT];
    __shared__ int rs[1 << SHIFT];
    int b = blockIdx.x;
    int t = threadIdx.x;
    int nb = b << SHIFT;
    int s0 = binStart[b];
    int s1 = binStart[b + 1];
    int cnt = s1 - s0;
    if (t < (1 << SHIFT)) cntN[t] = 0;
    bool st = (cnt <= CAP);
    __syncthreads();
    for (int i = t; i < cnt; i += 256) {
        int v = col[s0 + i];
        if (st) stage[i] = v;
        atomicAdd(&cntN[v & ((1 << SHIFT) - 1)], 1);
    }
    __syncthreads();
    if (t < (1 << SHIFT)) sc[t] = cntN[t];
    __syncthreads();
    #pragma unroll
    for (int off = 1; off < (1 << SHIFT); off <<= 1) {
        int w = 0;
        if (t < (1 << SHIFT) && t >= off) w = sc[t - off];
        __syncthreads();
        if (t < (1 << SHIFT)) sc[t] += w;
        __syncthreads();
    }
    if (t < (1 << SHIFT)) {
        int start = s0 + sc[t] - cntN[t];
        rs[t] = start;
        int node = nb + t;
        if (node < n) rowStart[node] = start;
        cntN[t] = 0;
    }
    __syncthreads();
    for (int i = t; i < cnt; i += 256) {
        int v = st ? stage[i] : col[s0 + i];
        int dl = v & ((1 << SHIFT) - 1);
        int r = atomicAdd(&cntN[dl], 1);
        col[rs[dl] + r] = v >> SHIFT;
    }
}

// ---------------------------------------------------------------------------
// K3: fused gather + combine, layers 1/2 — float4 lanes (4 lanes per edge).
__global__ void k_gc(const int* __restrict__ col, const int* __restrict__ rowStart,
                     const float* __restrict__ hin,
                     const void* __restrict__ Wl, const void* __restrict__ bia,
                     const void* __restrict__ Wr, const int* __restrict__ flags,
                     float* __restrict__ hout, int n, int e) {
    __shared__ float wl[HID][HID + 1], wr[HID][HID + 1], bb[HID];
    int t = threadIdx.x;
    int isbf = flags[1];
    if (t < HID * HID) {
        wl[t >> 4][t & 15] = ldw(Wl, t, isbf);
        wr[t >> 4][t & 15] = ldw(Wr, t, isbf);
    }
    if (t < HID) bb[t] = ldw(bia, t, isbf);
    __syncthreads();
    int node = blockIdx.x * 4 + (t >> 6);
    if (node >= n) return;
    int lane = t & 63;
    int q = lane & 3;
    int sg = lane >> 2;
    int lo = rowStart[node];
    int hi = (node + 1 < n) ? rowStart[node + 1] : e;
    const float4* h4 = (const float4*)hin;
    float4 acc = make_float4(0.f, 0.f, 0.f, 0.f);
    for (int i = lo + sg; i < hi; i += 16) {
        int s = col[i];
        float4 v = h4[(size_t)s * 4 + q];
        acc.x += v.x; acc.y += v.y; acc.z += v.z; acc.w += v.w;
    }
    #pragma unroll
    for (int d = 4; d < 64; d <<= 1) {
        acc.x += __shfl_xor(acc.x, d);
        acc.y += __shfl_xor(acc.y, d);
        acc.z += __shfl_xor(acc.z, d);
        acc.w += __shfl_xor(acc.w, d);
    }
    float inv = 1.0f / fmaxf((float)(hi - lo), 1.0f);
    float a4[4] = {acc.x * inv, acc.y * inv, acc.z * inv, acc.w * inv};
    float4 hbv = h4[(size_t)node * 4 + q];
    float hb4[4] = {hbv.x, hbv.y, hbv.z, hbv.w};
    int f = lane & 15;
    float o = bb[f];
    #pragma unroll
    for (int k = 0; k < HID; k++) {
        float ak = __shfl(a4[k & 3], k >> 2);
        float hk = __shfl(hb4[k & 3], k >> 2);
        o += ak * wl[f][k] + hk * wr[f][k];
    }
    float sq = o * o;
    #pragma unroll
    for (int d = 1; d < 16; d <<= 1) sq += __shfl_xor(sq, d);
    float innorm = 1.0f / fmaxf(sqrtf(sq), 1e-12f);
    o = fmaxf(o * innorm, 0.0f);
    if (lane < HID) hout[(size_t)node * HID + lane] = o;
}

// K4: layer-3 variant (10 outputs, zero-padded weight rows, no ReLU).
__global__ void k_gc3(const int* __restrict__ col, const int* __restrict__ rowStart,
                      const float* __restrict__ hin,
                      const void* __restrict__ Wl, const void* __restrict__ bia,
                      const void* __restrict__ Wr, const int* __restrict__ flags,
                      float* __restrict__ h3, int n, int e) {
    __shared__ float wl[HID][HID + 1], wr[HID][HID + 1], bb[HID];
    int t = threadIdx.x;
    int isbf = flags[1];
    if (t < HID * HID) {
        int r = t >> 4, c = t & 15;
        wl[r][c] = (r < NCLS) ? ldw(Wl, r * HID + c, isbf) : 0.0f;
        wr[r][c] = (r < NCLS) ? ldw(Wr, r * HID + c, isbf) : 0.0f;
    }
    if (t < HID) bb[t] = (t < NCLS) ? ldw(bia, t, isbf) : 0.0f;
    __syncthreads();
    int node = blockIdx.x * 4 + (t >> 6);
    if (node >= n) return;
    int lane = t & 63;
    int q = lane & 3;
    int sg = lane >> 2;
    int lo = rowStart[node];
    int hi = (node + 1 < n) ? rowStart[node + 1] : e;
    const float4* h4 = (const float4*)hin;
    float4 acc = make_float4(0.f, 0.f, 0.f, 0.f);
    for (int i = lo + sg; i < hi; i += 16) {
        int s = col[i];
        float4 v = h4[(size_t)s * 4 + q];
        acc.x += v.x; acc.y += v.y; acc.z += v.z; acc.w += v.w;
    }
    #pragma unroll
    for (int d = 4; d < 64; d <<= 1) {
        acc.x += __shfl_xor(acc.x, d);
        acc.y += __shfl_xor(acc.y, d);
        acc.z += __shfl_xor(acc.z, d);
        acc.w += __shfl_xor(acc.w, d);
    }
    float inv = 1.0f / fmaxf((float)(hi - lo), 1.0f);
    float a4[4] = {acc.x * inv, acc.y * inv, acc.z * inv, acc.w * inv};
    float4 hbv = h4[(size_t)node * 4 + q];
    float hb4[4] = {hbv.x, hbv.y, hbv.z, hbv.w};
    int f = lane & 15;
    float o = bb[f];
    #pragma unroll
    for (int k = 0; k < HID; k++) {
        float ak = __shfl(a4[k & 3], k >> 2);
        float hk = __shfl(hb4[k & 3], k >> 2);
        o += ak * wl[f][k] + hk * wr[f][k];
    }
    float sq = o * o;
    #pragma unroll
    for (int d = 1; d < 16; d <<= 1) sq += __shfl_xor(sq, d);
    float innorm = 1.0f / fmaxf(sqrtf(sq), 1e-12f);
    o = o * innorm;
    if (lane < NCLS) h3[(size_t)node * NCLS + lane] = o;
}

// ---------------------------------------------------------------------------
// K5: per-graph mean pool (batch sorted -> binary search) + softmax.
__device__ __forceinline__ int lbound(const int* __restrict__ a, int n, int key, int sh) {
    int lo = 0, hi = n;
    while (lo < hi) {
        int mid = (lo + hi) >> 1;
        if (a[((size_t)mid) << sh] < key) lo = mid + 1; else hi = mid;
    }
    return lo;
}

__global__ void k_pool_softmax(const float* __restrict__ h3,
                               const int* __restrict__ batch,
                               const int* __restrict__ flags,
                               void* __restrict__ out, int n) {
    int g = blockIdx.x;
    int lane = threadIdx.x;
    int sh = flags[0];
    int lo = lbound(batch, n, g, sh);
    int hi = lbound(batch, n, g + 1, sh);
    float acc[NCLS];
    #pragma unroll
    for (int c = 0; c < NCLS; c++) acc[c] = 0.0f;
    for (int i = lo + lane; i < hi; i += 64) {
        const float* r = h3 + (size_t)i * NCLS;
        #pragma unroll
        for (int c = 0; c < NCLS; c++) acc[c] += r[c];
    }
    #pragma unroll
    for (int c = 0; c < NCLS; c++) {
        #pragma unroll
        for (int off = 1; off < 64; off <<= 1)
            acc[c] += __shfl_xor(acc[c], off);
    }
    float invc = 1.0f / fmaxf((float)(hi - lo), 1.0f);
    float m = -1e30f;
    #pragma unroll
    for (int c = 0; c < NCLS; c++) { acc[c] *= invc; m = fmaxf(m, acc[c]); }
    float s = 0.0f;
    #pragma unroll
    for (int c = 0; c < NCLS; c++) { acc[c] = expf(acc[c] - m); s += acc[c]; }
    float invs = 1.0f / s;
    if (lane < NCLS) {
        float v = acc[lane] * invs;
        size_t idx = (size_t)g * NCLS + lane;
        if (flags[1]) ((__hip_bfloat16*)out)[idx] = __float2bfloat16(v);
        else          ((float*)out)[idx] = v;
    }
}

// ---------------------------------------------------------------------------
extern "C" void kernel_launch(void* const* d_in, const int* in_sizes, int n_in,
                              void* d_out, int out_size, void* d_ws, size_t ws_size,
                              hipStream_t stream) {
    const void* x   = d_in[0];
    const int*  ei  = (const int*)d_in[1];
    const int*  bat = (const int*)d_in[2];
    const void* emb = d_in[3];
    const void* W1l = d_in[4];  const void* b1 = d_in[5];  const void* W1r = d_in[6];
    const void* W2l = d_in[7];  const void* b2 = d_in[8];  const void* W2r = d_in[9];
    const void* W3l = d_in[10]; const void* b3 = d_in[11]; const void* W3r = d_in[12];

    int n = in_sizes[0] / N_FEAT;
    int e = in_sizes[1] / 2;
    int nbins = (n + (1 << SHIFT) - 1) >> SHIFT;
    int nblk  = (e + CH - 1) / CH;

    // ws: hcur[16n] f | hnext[16n] f (h3 aliased) | col[e] | rowStart[n] |
    //     binCnt[nbins] | binStart[nbins+1] | rbBuf[nblk*nbins] | flags[2]
    float* hcur     = (float*)d_ws;
    float* hnext    = hcur + (size_t)n * HID;
    int*   col      = (int*)(hnext + (size_t)n * HID);
    int*   rowStart = col + e;
    int*   binCnt   = rowStart + n;
    int*   binStart = binCnt + nbins;
    int*   rbBuf    = binStart + (nbins + 1);
    int*   flags    = rbBuf + (size_t)nblk * nbins;
    float* h3       = hnext;

    int ngrid4 = (n + 3) / 4;

    // probes + CSR build (hist -> per-bin scan -> bin scan -> place x2)
    k_detect<<<1, 64, 0, stream>>>(ei, (const unsigned int*)x, flags);
    k_binhist<<<nblk, 256, 0, stream>>>(ei, flags, rbBuf, e, nbins);
    k_colscan<<<nbins, 1024, 0, stream>>>(rbBuf, binCnt, nblk, nbins);
    k_scanbins<<<1, 1024, 0, stream>>>(binCnt, binStart, nbins, e);
    k_binplace<<<nblk, 256, 0, stream>>>(ei, flags, binStart, rbBuf, col, e, nbins);
    k_place<<<nbins, 256, 0, stream>>>(col, binStart, rowStart, n, e);

    // initial embedding
    k_argmax_embed<<<ngrid4, 256, 0, stream>>>(x, emb, flags, hcur, n);

    // 3 fused gather+combine layers
    k_gc <<<ngrid4, 256, 0, stream>>>(col, rowStart, hcur,  W1l, b1, W1r, flags, hnext, n, e);
    k_gc <<<ngrid4, 256, 0, stream>>>(col, rowStart, hnext, W2l, b2, W2r, flags, hcur,  n, e);
    k_gc3<<<ngrid4, 256, 0, stream>>>(col, rowStart, hcur,  W3l, b3, W3r, flags, h3,    n, e);

    // pool + softmax
    k_pool_softmax<<<NGRAPH, 64, 0, stream>>>(h3, bat, flags, d_out, n);
}

// Round 8
// 632.031 us; speedup vs baseline: 2.4355x; 1.0040x over previous
//
#include <hip/hip_runtime.h>
#include <hip/hip_bf16.h>

#define N_FEAT 128
#define HID 16
#define NCLS 10
#define NGRAPH 1024
#define SHIFT 7            // 128 nodes per coarse bin
#define NBMAX 1024         // supports n <= 131072
#define CAP 24576          // LDS staging entries in k_place (96 KB)
#define CH 8192            // edges per binning block
#define EPB (CH / 256)     // edges per thread in binning kernels

__device__ __forceinline__ float u2f(unsigned int u) {
    union { unsigned int u; float f; } c; c.u = u; return c.f;
}
__device__ __forceinline__ float bf2f(__hip_bfloat16 b) {
    return __bfloat162float(b);
}
__device__ __forceinline__ unsigned short f2us(float f) {
    union { __hip_bfloat16 b; unsigned short u; } c;
    c.b = __float2bfloat16(f);
    return c.u;
}
__device__ __forceinline__ float ldw(const void* __restrict__ p, int i, int isbf) {
    return isbf ? bf2f(((const __hip_bfloat16*)p)[i]) : ((const float*)p)[i];
}
// accumulate 8 bf16 packed in a uint4 into a[0..7]
__device__ __forceinline__ void acc8(uint4 v, float* a) {
    a[0] += u2f(v.x << 16); a[1] += u2f(v.x & 0xffff0000u);
    a[2] += u2f(v.y << 16); a[3] += u2f(v.y & 0xffff0000u);
    a[4] += u2f(v.z << 16); a[5] += u2f(v.z & 0xffff0000u);
    a[6] += u2f(v.w << 16); a[7] += u2f(v.w & 0xffff0000u);
}

// ---------------------------------------------------------------------------
// K0: runtime dtype probes (kept — these made R3 pass).
__global__ void k_detect(const int* __restrict__ ei,
                         const unsigned int* __restrict__ xw,
                         int* __restrict__ flags) {
    if (blockIdx.x == 0 && threadIdx.x == 0) {
        int nz = 0;
        for (int i = 1; i < 256; i += 2) nz |= ei[i];
        flags[0] = (nz == 0) ? 1 : 0;
        int cnt = 0;
        for (int i = 0; i < 64; i++) {
            unsigned int ef = xw[i] & 0x7F80u;
            if (ef >= 0x3C00u && ef <= 0x4080u) cnt++;
        }
        flags[1] = (cnt >= 32) ? 1 : 0;
    }
}

// ---------------------------------------------------------------------------
// K1: h0[i] = emb[argmax(x[i,:])] — one 64-lane wave per node; bf16 output.
__global__ void k_argmax_embed(const void* __restrict__ x,
                               const void* __restrict__ emb,
                               const int* __restrict__ flags,
                               unsigned short* __restrict__ h, int n) {
    int wave = (int)((blockIdx.x * (unsigned)blockDim.x + threadIdx.x) >> 6);
    int lane = threadIdx.x & 63;
    if (wave >= n) return;
    int isbf = flags[1];
    float v0, v1;
    if (isbf) {
        const unsigned int* row =
            (const unsigned int*)((const __hip_bfloat16*)x + (size_t)wave * N_FEAT);
        unsigned int u = row[lane];
        v0 = u2f(u << 16);
        v1 = u2f(u & 0xffff0000u);
    } else {
        const float2* row = (const float2*)((const float*)x + (size_t)wave * N_FEAT);
        float2 u = row[lane];
        v0 = u.x; v1 = u.y;
    }
    float bv; int bi;
    if (v1 > v0) { bv = v1; bi = 2 * lane + 1; }
    else         { bv = v0; bi = 2 * lane; }
    #pragma unroll
    for (int off = 1; off < 64; off <<= 1) {
        float ov = __shfl_xor(bv, off);
        int   oi = __shfl_xor(bi, off);
        if (ov > bv || (ov == bv && oi < bi)) { bv = ov; bi = oi; }
    }
    if (lane < HID) {
        unsigned short us;
        if (isbf) us = ((const unsigned short*)emb)[bi * HID + lane];  // exact copy
        else      us = f2us(((const float*)emb)[bi * HID + lane]);
        h[(size_t)wave * HID + lane] = us;
    }
}

// ---------------------------------------------------------------------------
// K2a: per-block LDS bin histogram -> plain coalesced store of the count row.
__global__ void k_binhist(const int* __restrict__ ei, const int* __restrict__ flags,
                          int* __restrict__ rbBuf, int e, int nbins) {
    __shared__ int lh[NBMAX];
    int t = threadIdx.x;
    for (int b = t; b < nbins; b += 256) lh[b] = 0;
    __syncthreads();
    int base = blockIdx.x * CH;
    int sh = flags[0];
    for (int j = 0; j < EPB; j++) {
        int i = base + j * 256 + t;
        if (i < e) {
            int d = ei[((size_t)(e + i)) << sh];
            atomicAdd(&lh[d >> SHIFT], 1);
        }
    }
    __syncthreads();
    int* row = rbBuf + (size_t)blockIdx.x * nbins;
    for (int b = t; b < nbins; b += 256) row[b] = lh[b];
}

// K2b: per-bin exclusive scan over blocks (in place).
__global__ void k_colscan(int* __restrict__ rbBuf, int* __restrict__ binCnt,
                          int nblk, int nbins) {
    __shared__ int ls[1024];
    int b = blockIdx.x, t = threadIdx.x;
    int v = (t < nblk) ? rbBuf[(size_t)t * nbins + b] : 0;
    ls[t] = v;
    __syncthreads();
    #pragma unroll
    for (int off = 1; off < 1024; off <<= 1) {
        int w = (t >= off) ? ls[t - off] : 0;
        __syncthreads();
        ls[t] += w;
        __syncthreads();
    }
    if (t < nblk) rbBuf[(size_t)t * nbins + b] = ls[t] - v;
    if (t == 1023) binCnt[b] = ls[t];
}

// K2c: exclusive scan of binCnt -> binStart.
__global__ void k_scanbins(const int* __restrict__ binCnt,
                           int* __restrict__ binStart, int nbins, int e) {
    __shared__ int ls[1024];
    int t = threadIdx.x;
    int v = (t < nbins) ? binCnt[t] : 0;
    ls[t] = v;
    __syncthreads();
    #pragma unroll
    for (int off = 1; off < 1024; off <<= 1) {
        int w = (t >= off) ? ls[t - off] : 0;
        __syncthreads();
        ls[t] += w;
        __syncthreads();
    }
    if (t < nbins) binStart[t] = ls[t] - v;
    if (t == 0) binStart[nbins] = e;
}

// K2d: coarse placement, LDS-sorted for coalesced writes (R7 win — kept).
__global__ __launch_bounds__(256) void k_binplace(
        const int* __restrict__ ei, const int* __restrict__ flags,
        const int* __restrict__ binStart, const int* __restrict__ rbBuf,
        int* __restrict__ col, int e, int nbins) {
    __shared__ int cnt[NBMAX];
    __shared__ int ldsOff[NBMAX];
    __shared__ int ldsBase[NBMAX];
    __shared__ int ps[256];
    __shared__ int stage[CH];
    __shared__ unsigned short binOf[CH];
    int t = threadIdx.x;
    for (int b = t; b < nbins; b += 256) cnt[b] = 0;
    __syncthreads();
    int base = blockIdx.x * CH;
    int sh = flags[0];
    int myV[EPB]; short myB[EPB];
    for (int j = 0; j < EPB; j++) {
        int i = base + j * 256 + t;
        if (i < e) {
            int s = ei[((size_t)i) << sh];
            int d = ei[((size_t)(e + i)) << sh];
            myV[j] = (s << SHIFT) | (d & ((1 << SHIFT) - 1));
            int b2 = d >> SHIFT;
            myB[j] = (short)b2;
            atomicAdd(&cnt[b2], 1);
        } else myB[j] = -1;
    }
    __syncthreads();
    int c[4]; int lsum = 0;
    int bb = t * 4;
    #pragma unroll
    for (int k = 0; k < 4; k++) {
        int b2 = bb + k;
        c[k] = (b2 < nbins) ? cnt[b2] : 0;
        lsum += c[k];
    }
    ps[t] = lsum;
    __syncthreads();
    #pragma unroll
    for (int off = 1; off < 256; off <<= 1) {
        int w = (t >= off) ? ps[t - off] : 0;
        __syncthreads();
        ps[t] += w;
        __syncthreads();
    }
    int run = ps[t] - lsum;
    #pragma unroll
    for (int k = 0; k < 4; k++) {
        int b2 = bb + k;
        if (b2 < nbins) ldsOff[b2] = run;
        run += c[k];
    }
    __syncthreads();
    const int* rb = rbBuf + (size_t)blockIdx.x * nbins;
    for (int b2 = t; b2 < nbins; b2 += 256) {
        ldsBase[b2] = binStart[b2] + rb[b2] - ldsOff[b2];
        cnt[b2] = 0;
    }
    __syncthreads();
    for (int j = 0; j < EPB; j++) {
        if (myB[j] >= 0) {
            int b2 = myB[j];
            int r = atomicAdd(&cnt[b2], 1);
            int p = ldsOff[b2] + r;
            stage[p] = myV[j];
            binOf[p] = (unsigned short)b2;
        }
    }
    __syncthreads();
    int total = e - base;
    if (total > CH) total = CH;
    for (int i = t; i < total; i += 256) {
        int b2 = binOf[i];
        col[ldsBase[b2] + i] = stage[i];
    }
}

// K2e: fine placement + per-node rowStart.
__global__ void k_place(int* __restrict__ col, const int* __restrict__ binStart,
                        int* __restrict__ rowStart, int n, int e) {
    __shared__ int stage[CAP];
    __shared__ int cntN[1 << SHIFT];
    __shared__ int sc[1 << SHIFT];
    __shared__ int rs[1 << SHIFT];
    int b = blockIdx.x;
    int t = threadIdx.x;
    int nb = b << SHIFT;
    int s0 = binStart[b];
    int s1 = binStart[b + 1];
    int cnt = s1 - s0;
    if (t < (1 << SHIFT)) cntN[t] = 0;
    bool st = (cnt <= CAP);
    __syncthreads();
    for (int i = t; i < cnt; i += 256) {
        int v = col[s0 + i];
        if (st) stage[i] = v;
        atomicAdd(&cntN[v & ((1 << SHIFT) - 1)], 1);
    }
    __syncthreads();
    if (t < (1 << SHIFT)) sc[t] = cntN[t];
    __syncthreads();
    #pragma unroll
    for (int off = 1; off < (1 << SHIFT); off <<= 1) {
        int w = 0;
        if (t < (1 << SHIFT) && t >= off) w = sc[t - off];
        __syncthreads();
        if (t < (1 << SHIFT)) sc[t] += w;
        __syncthreads();
    }
    if (t < (1 << SHIFT)) {
        int start = s0 + sc[t] - cntN[t];
        rs[t] = start;
        int node = nb + t;
        if (node < n) rowStart[node] = start;
        cntN[t] = 0;
    }
    __syncthreads();
    for (int i = t; i < cnt; i += 256) {
        int v = st ? stage[i] : col[s0 + i];
        int dl = v & ((1 << SHIFT) - 1);
        int r = atomicAdd(&cntN[dl], 1);
        col[rs[dl] + r] = v >> SHIFT;
    }
}

// ---------------------------------------------------------------------------
// K3: fused gather + combine, layers 1/2. h table is bf16 (32 B rows -> fits
// per-XCD L2); col reads are non-temporal to avoid evicting it.
// 2 lanes per edge (q=lane&1 picks 16B half-row), 32 edge walkers per wave.
__global__ void k_gc(const int* __restrict__ col, const int* __restrict__ rowStart,
                     const unsigned short* __restrict__ hin,
                     const void* __restrict__ Wl, const void* __restrict__ bia,
                     const void* __restrict__ Wr, const int* __restrict__ flags,
                     unsigned short* __restrict__ hout, int n, int e) {
    __shared__ float wl[HID][HID + 1], wr[HID][HID + 1], bb[HID];
    int t = threadIdx.x;
    int isbf = flags[1];
    if (t < HID * HID) {
        wl[t >> 4][t & 15] = ldw(Wl, t, isbf);
        wr[t >> 4][t & 15] = ldw(Wr, t, isbf);
    }
    if (t < HID) bb[t] = ldw(bia, t, isbf);
    __syncthreads();
    int node = blockIdx.x * 4 + (t >> 6);
    if (node >= n) return;
    int lane = t & 63;
    int q = lane & 1;
    int sg = lane >> 1;
    int lo = rowStart[node];
    int hi = (node + 1 < n) ? rowStart[node + 1] : e;
    const uint4* h4 = (const uint4*)hin;      // 2 uint4 per 32B row
    float a[8] = {0, 0, 0, 0, 0, 0, 0, 0};
    for (int i = lo + sg; i < hi; i += 32) {
        int s = __builtin_nontemporal_load(col + i);
        uint4 v = h4[((size_t)s << 1) | q];
        acc8(v, a);
    }
    #pragma unroll
    for (int d = 2; d < 64; d <<= 1) {
        #pragma unroll
        for (int j = 0; j < 8; j++) a[j] += __shfl_xor(a[j], d);
    }
    float inv = 1.0f / fmaxf((float)(hi - lo), 1.0f);
    #pragma unroll
    for (int j = 0; j < 8; j++) a[j] *= inv;
    float hb[8] = {0, 0, 0, 0, 0, 0, 0, 0};
    uint4 hv = h4[((size_t)node << 1) | q];
    acc8(hv, hb);
    int f = lane & 15;
    float o = bb[f];
    #pragma unroll
    for (int k = 0; k < HID; k++) {
        float ak = __shfl(a[k & 7], k >> 3);   // lane 0 (q=0) or 1 (q=1)
        float hk = __shfl(hb[k & 7], k >> 3);
        o += ak * wl[f][k] + hk * wr[f][k];
    }
    float sq = o * o;
    #pragma unroll
    for (int d = 1; d < 16; d <<= 1) sq += __shfl_xor(sq, d);
    float innorm = 1.0f / fmaxf(sqrtf(sq), 1e-12f);
    o = fmaxf(o * innorm, 0.0f);
    if (lane < HID) hout[(size_t)node * HID + lane] = f2us(o);
}

// K4: layer-3 variant (10 outputs, zero-padded weight rows, no ReLU; fp32 out).
__global__ void k_gc3(const int* __restrict__ col, const int* __restrict__ rowStart,
                      const unsigned short* __restrict__ hin,
                      const void* __restrict__ Wl, const void* __restrict__ bia,
                      const void* __restrict__ Wr, const int* __restrict__ flags,
                      float* __restrict__ h3, int n, int e) {
    __shared__ float wl[HID][HID + 1], wr[HID][HID + 1], bb[HID];
    int t = threadIdx.x;
    int isbf = flags[1];
    if (t < HID * HID) {
        int r = t >> 4, c = t & 15;
        wl[r][c] = (r < NCLS) ? ldw(Wl, r * HID + c, isbf) : 0.0f;
        wr[r][c] = (r < NCLS) ? ldw(Wr, r * HID + c, isbf) : 0.0f;
    }
    if (t < HID) bb[t] = (t < NCLS) ? ldw(bia, t, isbf) : 0.0f;
    __syncthreads();
    int node = blockIdx.x * 4 + (t >> 6);
    if (node >= n) return;
    int lane = t & 63;
    int q = lane & 1;
    int sg = lane >> 1;
    int lo = rowStart[node];
    int hi = (node + 1 < n) ? rowStart[node + 1] : e;
    const uint4* h4 = (const uint4*)hin;
    float a[8] = {0, 0, 0, 0, 0, 0, 0, 0};
    for (int i = lo + sg; i < hi; i += 32) {
        int s = __builtin_nontemporal_load(col + i);
        uint4 v = h4[((size_t)s << 1) | q];
        acc8(v, a);
    }
    #pragma unroll
    for (int d = 2; d < 64; d <<= 1) {
        #pragma unroll
        for (int j = 0; j < 8; j++) a[j] += __shfl_xor(a[j], d);
    }
    float inv = 1.0f / fmaxf((float)(hi - lo), 1.0f);
    #pragma unroll
    for (int j = 0; j < 8; j++) a[j] *= inv;
    float hb[8] = {0, 0, 0, 0, 0, 0, 0, 0};
    uint4 hv = h4[((size_t)node << 1) | q];
    acc8(hv, hb);
    int f = lane & 15;
    float o = bb[f];
    #pragma unroll
    for (int k = 0; k < HID; k++) {
        float ak = __shfl(a[k & 7], k >> 3);
        float hk = __shfl(hb[k & 7], k >> 3);
        o += ak * wl[f][k] + hk * wr[f][k];
    }
    float sq = o * o;              // rows >= NCLS give o = 0
    #pragma unroll
    for (int d = 1; d < 16; d <<= 1) sq += __shfl_xor(sq, d);
    float innorm = 1.0f / fmaxf(sqrtf(sq), 1e-12f);
    o = o * innorm;
    if (lane < NCLS) h3[(size_t)node * NCLS + lane] = o;
}

// ---------------------------------------------------------------------------
// K5: per-graph mean pool (batch sorted -> binary search) + softmax.
__device__ __forceinline__ int lbound(const int* __restrict__ a, int n, int key, int sh) {
    int lo = 0, hi = n;
    while (lo < hi) {
        int mid = (lo + hi) >> 1;
        if (a[((size_t)mid) << sh] < key) lo = mid + 1; else hi = mid;
    }
    return lo;
}

__global__ void k_pool_softmax(const float* __restrict__ h3,
                               const int* __restrict__ batch,
                               const int* __restrict__ flags,
                               void* __restrict__ out, int n) {
    int g = blockIdx.x;
    int lane = threadIdx.x;
    int sh = flags[0];
    int lo = lbound(batch, n, g, sh);
    int hi = lbound(batch, n, g + 1, sh);
    float acc[NCLS];
    #pragma unroll
    for (int c = 0; c < NCLS; c++) acc[c] = 0.0f;
    for (int i = lo + lane; i < hi; i += 64) {
        const float* r = h3 + (size_t)i * NCLS;
        #pragma unroll
        for (int c = 0; c < NCLS; c++) acc[c] += r[c];
    }
    #pragma unroll
    for (int c = 0; c < NCLS; c++) {
        #pragma unroll
        for (int off = 1; off < 64; off <<= 1)
            acc[c] += __shfl_xor(acc[c], off);
    }
    float invc = 1.0f / fmaxf((float)(hi - lo), 1.0f);
    float m = -1e30f;
    #pragma unroll
    for (int c = 0; c < NCLS; c++) { acc[c] *= invc; m = fmaxf(m, acc[c]); }
    float s = 0.0f;
    #pragma unroll
    for (int c = 0; c < NCLS; c++) { acc[c] = expf(acc[c] - m); s += acc[c]; }
    float invs = 1.0f / s;
    if (lane < NCLS) {
        float v = acc[lane] * invs;
        size_t idx = (size_t)g * NCLS + lane;
        if (flags[1]) ((__hip_bfloat16*)out)[idx] = __float2bfloat16(v);
        else          ((float*)out)[idx] = v;
    }
}

// ---------------------------------------------------------------------------
extern "C" void kernel_launch(void* const* d_in, const int* in_sizes, int n_in,
                              void* d_out, int out_size, void* d_ws, size_t ws_size,
                              hipStream_t stream) {
    const void* x   = d_in[0];
    const int*  ei  = (const int*)d_in[1];
    const int*  bat = (const int*)d_in[2];
    const void* emb = d_in[3];
    const void* W1l = d_in[4];  const void* b1 = d_in[5];  const void* W1r = d_in[6];
    const void* W2l = d_in[7];  const void* b2 = d_in[8];  const void* W2r = d_in[9];
    const void* W3l = d_in[10]; const void* b3 = d_in[11]; const void* W3r = d_in[12];

    int n = in_sizes[0] / N_FEAT;
    int e = in_sizes[1] / 2;
    int nbins = (n + (1 << SHIFT) - 1) >> SHIFT;
    int nblk  = (e + CH - 1) / CH;

    // ws: hcur[16n] bf16 | hnext[16n] bf16 | h3[10n] f32 | col[e] |
    //     rowStart[n] | binCnt | binStart | rbBuf[nblk*nbins] | flags
    unsigned short* hcur  = (unsigned short*)d_ws;
    unsigned short* hnext = hcur + (size_t)n * HID;
    float* h3       = (float*)(hnext + (size_t)n * HID);
    int*   col      = (int*)(h3 + (size_t)n * NCLS);
    int*   rowStart = col + e;
    int*   binCnt   = rowStart + n;
    int*   binStart = binCnt + nbins;
    int*   rbBuf    = binStart + (nbins + 1);
    int*   flags    = rbBuf + (size_t)nblk * nbins;

    int ngrid4 = (n + 3) / 4;

    // probes + CSR build
    k_detect<<<1, 64, 0, stream>>>(ei, (const unsigned int*)x, flags);
    k_binhist<<<nblk, 256, 0, stream>>>(ei, flags, rbBuf, e, nbins);
    k_colscan<<<nbins, 1024, 0, stream>>>(rbBuf, binCnt, nblk, nbins);
    k_scanbins<<<1, 1024, 0, stream>>>(binCnt, binStart, nbins, e);
    k_binplace<<<nblk, 256, 0, stream>>>(ei, flags, binStart, rbBuf, col, e, nbins);
    k_place<<<nbins, 256, 0, stream>>>(col, binStart, rowStart, n, e);

    // initial embedding (bf16 h table)
    k_argmax_embed<<<ngrid4, 256, 0, stream>>>(x, emb, flags, hcur, n);

    // 3 fused gather+combine layers (bf16 h, nt col reads)
    k_gc <<<ngrid4, 256, 0, stream>>>(col, rowStart, hcur,  W1l, b1, W1r, flags, hnext, n, e);
    k_gc <<<ngrid4, 256, 0, stream>>>(col, rowStart, hnext, W2l, b2, W2r, flags, hcur,  n, e);
    k_gc3<<<ngrid4, 256, 0, stream>>>(col, rowStart, hcur,  W3l, b3, W3r, flags, h3,    n, e);

    // pool + softmax
    k_pool_softmax<<<NGRAPH, 64, 0, stream>>>(h3, bat, flags, d_out, n);
}